// Round 7
// baseline (230.569 us; speedup 1.0000x reference)
//
#include <hip/hip_runtime.h>

#define NUM_K 64
#define CDIM 32
#define HW 16384          // 128*128
#define NPTS 1048576      // 64*128*128
#define NELEMD 33554432.0 // 64*32*128*128

#define FOR32(M) M(0) M(1) M(2) M(3) M(4) M(5) M(6) M(7) \
                 M(8) M(9) M(10) M(11) M(12) M(13) M(14) M(15) \
                 M(16) M(17) M(18) M(19) M(20) M(21) M(22) M(23) \
                 M(24) M(25) M(26) M(27) M(28) M(29) M(30) M(31)

// Single kernel: staging + B_k + argmin + gather + loss + last-block finish.
// ALL per-point state is in named scalars -> guaranteed VGPR residency (no
// array for the compiler to scratch-allocate or rematerialize from global).
__global__ __launch_bounds__(256) void vq_main(const float* __restrict__ x,
                                               const float* __restrict__ emb,
                                               float* __restrict__ outq,   // out+1
                                               float* __restrict__ outLoss,// out+0
                                               double* __restrict__ ws) {
#pragma clang fp contract(off)
    __shared__ float sET[CDIM][NUM_K];  // transposed codebook for the divergent gather
    __shared__ float sB[NUM_K];         // np.sum(emb*emb, axis=1), numpy fp32 order
    __shared__ float sRed[4];

    const int t = threadIdx.x;
    // Conflict-free LDS staging: thread i writes flat addr i (bank i%32).
    for (int i = t; i < NUM_K * CDIM; i += 256) {
        int c = i >> 6, k = i & 63;
        ((float*)sET)[i] = emb[k * CDIM + c];   // sET[c][k]
    }
    if (t < NUM_K) {
        const float* e = emb + t * CDIM;
#define LE(c) float se##c = e[c];
        FOR32(LE)
#undef LE
        float b0 = ((se0*se0 + se8*se8) + se16*se16) + se24*se24;
        float b1 = ((se1*se1 + se9*se9) + se17*se17) + se25*se25;
        float b2 = ((se2*se2 + se10*se10) + se18*se18) + se26*se26;
        float b3 = ((se3*se3 + se11*se11) + se19*se19) + se27*se27;
        float b4 = ((se4*se4 + se12*se12) + se20*se20) + se28*se28;
        float b5 = ((se5*se5 + se13*se13) + se21*se21) + se29*se29;
        float b6 = ((se6*se6 + se14*se14) + se22*se22) + se30*se30;
        float b7 = ((se7*se7 + se15*se15) + se23*se23) + se31*se31;
        sB[t] = ((b0 + b1) + (b2 + b3)) + ((b4 + b5) + (b6 + b7));
    }
    __syncthreads();

    const int p = blockIdx.x * 256 + t;
    const int b = p >> 14;
    const size_t base = (size_t)b * (CDIM * HW) + (p & (HW - 1));
    const float* xp = x + base;

    // 32 named scalars: the whole point of this round.
#define LX(c) float xv##c = xp[(size_t)(c) * HW];
    FOR32(LX)
#undef LX

    // A = np.sum(x*x, axis=1), numpy pairwise fp32 order (contract off: each
    // product rounds individually, adds in the written association).
    float r0 = ((xv0*xv0 + xv8*xv8) + xv16*xv16) + xv24*xv24;
    float r1 = ((xv1*xv1 + xv9*xv9) + xv17*xv17) + xv25*xv25;
    float r2 = ((xv2*xv2 + xv10*xv10) + xv18*xv18) + xv26*xv26;
    float r3 = ((xv3*xv3 + xv11*xv11) + xv19*xv19) + xv27*xv27;
    float r4 = ((xv4*xv4 + xv12*xv12) + xv20*xv20) + xv28*xv28;
    float r5 = ((xv5*xv5 + xv13*xv13) + xv21*xv21) + xv29*xv29;
    float r6 = ((xv6*xv6 + xv14*xv14) + xv22*xv22) + xv30*xv30;
    float r7 = ((xv7*xv7 + xv15*xv15) + xv23*xv23) + xv31*xv31;
    const float A = ((r0 + r1) + (r2 + r3)) + ((r4 + r5) + (r6 + r7));

    // d_k = fp32( fp32(A + B_k) - 2*C_k ); C_k = ascending-c sequential FMA
    // chain; fmaf(-2,acc,t1) == t1-(acc+acc) bitwise. Strict < ascending k =
    // first-min (np.argmin). Bit-identical to the passing round-3/4 kernels.
    float best = 3.4028235e38f;
    int bi = 0;
    #pragma unroll 4
    for (int k = 0; k < NUM_K; ++k) {
        const float* __restrict__ ek = emb + k * CDIM;  // uniform -> s_load -> SGPR
        float acc = 0.f;
#define CH(c) acc = fmaf(xv##c, ek[c], acc);
        FOR32(CH)
#undef CH
        float d = fmaf(-2.f, acc, A + sB[k]);
        if (d < best) { best = d; bi = k; }
    }

    // Gather winner + coalesced stores + loss partial.
    float* op = outq + base;
    float lsum = 0.f;
#define GL(c) { float q = sET[c][bi]; op[(size_t)(c) * HW] = q; \
                float f = q - xv##c; lsum = fmaf(f, f, lsum); }
    FOR32(GL)
#undef GL

    #pragma unroll
    for (int off = 32; off > 0; off >>= 1)
        lsum += __shfl_down(lsum, off, 64);
    const int wid = t >> 6;
    if ((t & 63) == 0) sRed[wid] = lsum;
    __syncthreads();
    if (t == 0) {
        double bs = (double)sRed[0] + (double)sRed[1] + (double)sRed[2] + (double)sRed[3];
        atomicAdd(ws, bs);
        __threadfence();                                  // order add before arrival
        unsigned* cnt = (unsigned*)(ws + 1);
        unsigned done = atomicAdd(cnt, 1u);
        if (done == gridDim.x - 1) {                      // last block finishes the loss
            unsigned long long bits =
                atomicAdd((unsigned long long*)ws, 0ull); // coherent RMW readback
            double total = __longlong_as_double(bits);
            outLoss[0] = (float)(1.25 * total / NELEMD);
        }
    }
}

extern "C" void kernel_launch(void* const* d_in, const int* in_sizes, int n_in,
                              void* d_out, int out_size, void* d_ws, size_t ws_size,
                              hipStream_t stream) {
    const float* x = (const float*)d_in[0];
    const float* emb = (const float*)d_in[1];
    float* out = (float*)d_out;
    double* ws = (double*)d_ws;   // ws[0]=loss accumulator, ws[1]=arrival counter

    hipMemsetAsync(d_ws, 0, 16, stream);   // zero accumulator + counter every call
    vq_main<<<NPTS / 256, 256, 0, stream>>>(x, emb, out + 1, out, ws);
}

// Round 8
// 118.489 us; speedup vs baseline: 1.9459x; 1.9459x over previous
//
#include <hip/hip_runtime.h>

#define NUM_K 64
#define CDIM 32
#define HW 16384          // 128*128
#define NPTS 1048576      // 64*128*128
#define NELEMD 33554432.0 // 64*32*128*128

#define FOR32(M) M(0) M(1) M(2) M(3) M(4) M(5) M(6) M(7) \
                 M(8) M(9) M(10) M(11) M(12) M(13) M(14) M(15) \
                 M(16) M(17) M(18) M(19) M(20) M(21) M(22) M(23) \
                 M(24) M(25) M(26) M(27) M(28) M(29) M(30) M(31)

// numpy pairwise sum of squares, n=32 contiguous: 8 accumulators + fixed tree.
__device__ __forceinline__ float np_sumsq32(const float* v) {
#pragma clang fp contract(off)
    float r[8];
    #pragma unroll
    for (int j = 0; j < 8; ++j) {
        float p0 = v[j] * v[j];
        float p1 = v[j + 8] * v[j + 8];
        float p2 = v[j + 16] * v[j + 16];
        float p3 = v[j + 24] * v[j + 24];
        r[j] = ((p0 + p1) + p2) + p3;
    }
    return ((r[0] + r[1]) + (r[2] + r[3])) + ((r[4] + r[5]) + (r[6] + r[7]));
}

__global__ void vq_prep(const float* __restrict__ emb, float* __restrict__ Bg) {
#pragma clang fp contract(off)
    int k = threadIdx.x;
    if (k < NUM_K) {
        float e[CDIM];
        #pragma unroll
        for (int c = 0; c < CDIM; ++c) e[c] = emb[k * CDIM + c];
        Bg[k] = np_sumsq32(e);
    }
}

__global__ __launch_bounds__(256) void vq_main(const float* __restrict__ x,
                                               const float* __restrict__ emb,
                                               const float* __restrict__ Bg,
                                               float* __restrict__ outq,
                                               double* __restrict__ ws) {
#pragma clang fp contract(off)
    __shared__ float sET[CDIM][NUM_K];  // transposed codebook for the divergent gather
    __shared__ float sRed[4];

    const int t = threadIdx.x;
    // Conflict-free LDS staging: thread i writes flat addr i (bank i%32).
    #pragma unroll
    for (int i = t; i < NUM_K * CDIM; i += 256) {
        int c = i >> 6, k = i & 63;
        ((float*)sET)[i] = emb[k * CDIM + c];   // sET[c][k]
    }
    __syncthreads();

    const int p = blockIdx.x * 256 + t;
    const int b = p >> 14;
    const size_t base = (size_t)b * (CDIM * HW) + (p & (HW - 1));
    const float* xp = x + base;

    // Load x once, then PIN each value in a VGPR via opaque empty asm.
    // The "+v" output makes the value non-rematerializable: the compiler can
    // no longer re-issue the global load inside the k-loop (the R3-R7
    // pathology: VGPR_Count=28 with 32 live floats => ~16x L1/L2 re-reads).
#define LXP(c) float xv##c = xp[(size_t)(c) * HW]; \
               asm volatile("" : "+v"(xv##c));
    FOR32(LXP)
#undef LXP

    // A = np.sum(x*x, axis=1), numpy pairwise fp32 order.
    float r0 = ((xv0*xv0 + xv8*xv8) + xv16*xv16) + xv24*xv24;
    float r1 = ((xv1*xv1 + xv9*xv9) + xv17*xv17) + xv25*xv25;
    float r2 = ((xv2*xv2 + xv10*xv10) + xv18*xv18) + xv26*xv26;
    float r3 = ((xv3*xv3 + xv11*xv11) + xv19*xv19) + xv27*xv27;
    float r4 = ((xv4*xv4 + xv12*xv12) + xv20*xv20) + xv28*xv28;
    float r5 = ((xv5*xv5 + xv13*xv13) + xv21*xv21) + xv29*xv29;
    float r6 = ((xv6*xv6 + xv14*xv14) + xv22*xv22) + xv30*xv30;
    float r7 = ((xv7*xv7 + xv15*xv15) + xv23*xv23) + xv31*xv31;
    const float A = ((r0 + r1) + (r2 + r3)) + ((r4 + r5) + (r6 + r7));

    // d_k = fp32( fp32(A + B_k) - 2*C_k ); C_k = ascending-c sequential FMA
    // chain; fmaf(-2,acc,t1) == t1-(acc+acc) bitwise. Strict < ascending k =
    // first-min (np.argmin). Bit-identical numerics to the passing rounds.
    float best = 3.4028235e38f;
    int bi = 0;
    #pragma unroll 4
    for (int k = 0; k < NUM_K; ++k) {
        const float* __restrict__ ek = emb + k * CDIM;  // uniform -> s_load -> SGPR
        float acc = 0.f;
#define CH(c) acc = fmaf(xv##c, ek[c], acc);
        FOR32(CH)
#undef CH
        float d = fmaf(-2.f, acc, A + Bg[k]);
        if (d < best) { best = d; bi = k; }
    }

    // Gather winner + coalesced stores + loss partial (uses the pinned regs).
    float* op = outq + base;
    float lsum = 0.f;
#define GL(c) { float q = sET[c][bi]; op[(size_t)(c) * HW] = q; \
                float f = q - xv##c; lsum = fmaf(f, f, lsum); }
    FOR32(GL)
#undef GL

    #pragma unroll
    for (int off = 32; off > 0; off >>= 1)
        lsum += __shfl_down(lsum, off, 64);
    const int wid = t >> 6;
    if ((t & 63) == 0) sRed[wid] = lsum;
    __syncthreads();
    if (t == 0) {
        double bs = (double)sRed[0] + (double)sRed[1] + (double)sRed[2] + (double)sRed[3];
        atomicAdd(ws, bs);
    }
}

__global__ void vq_finish(const double* __restrict__ ws, float* __restrict__ loss) {
    loss[0] = (float)(1.25 * ws[0] / NELEMD);
}

extern "C" void kernel_launch(void* const* d_in, const int* in_sizes, int n_in,
                              void* d_out, int out_size, void* d_ws, size_t ws_size,
                              hipStream_t stream) {
    const float* x = (const float*)d_in[0];
    const float* emb = (const float*)d_in[1];
    float* out = (float*)d_out;
    // ws layout: [0..7] double loss accumulator, [16..272) float B[64]
    double* acc = (double*)d_ws;
    float* Bg = (float*)((char*)d_ws + 16);

    hipMemsetAsync(d_ws, 0, sizeof(double), stream);  // zero accumulator every call
    vq_prep<<<1, 64, 0, stream>>>(emb, Bg);
    vq_main<<<NPTS / 256, 256, 0, stream>>>(x, emb, Bg, out + 1, acc);
    vq_finish<<<1, 1, 0, stream>>>(acc, out);
}

// Round 9
// 86.181 us; speedup vs baseline: 2.6754x; 1.3749x over previous
//
#include <hip/hip_runtime.h>

#define NUM_K 64
#define CDIM 32
#define HW 16384          // 128*128
#define NPTS 1048576      // 64*128*128
#define NELEMD 33554432.0 // 64*32*128*128

typedef float v2f __attribute__((ext_vector_type(2)));

// numpy pairwise sum of squares, n=32 contiguous: 8 accumulators + fixed tree.
__device__ __forceinline__ float np_sumsq32(const float* v) {
#pragma clang fp contract(off)
    float r[8];
    #pragma unroll
    for (int j = 0; j < 8; ++j) {
        float p0 = v[j] * v[j];
        float p1 = v[j + 8] * v[j + 8];
        float p2 = v[j + 16] * v[j + 16];
        float p3 = v[j + 24] * v[j + 24];
        r[j] = ((p0 + p1) + p2) + p3;
    }
    return ((r[0] + r[1]) + (r[2] + r[3])) + ((r[4] + r[5]) + (r[6] + r[7]));
}

// Prep: B[k] = np.sum(emb*emb,axis=1) (numpy fp32 order) and embT[c][k]
// (transposed codebook, contiguous in k) -> global scratch.
__global__ void vq_prep(const float* __restrict__ emb, float* __restrict__ Bg,
                        float* __restrict__ embT) {
#pragma clang fp contract(off)
    int k = threadIdx.x;
    if (k < NUM_K) {
        float e[CDIM];
        #pragma unroll
        for (int c = 0; c < CDIM; ++c) e[c] = emb[k * CDIM + c];
        Bg[k] = np_sumsq32(e);
        #pragma unroll
        for (int c = 0; c < CDIM; ++c) embT[c * NUM_K + k] = e[c];
    }
}

// Loop-interchanged main: c outer, k inner. Per c-step: 64 INDEPENDENT fma
// (32 float2 packed) -> no serial chain, x consumed immediately, accumulators
// un-rematerializable. Codebook row embT[c][*] = 256B contiguous uniform ->
// merged s_loads feeding the SGPR operand of v_fma.
__global__ __launch_bounds__(256) void vq_main(const float* __restrict__ x,
                                               const float* __restrict__ embT,
                                               const float* __restrict__ Bg,
                                               float* __restrict__ outq,
                                               double* __restrict__ ws) {
#pragma clang fp contract(off)
    __shared__ float sET[CDIM][NUM_K];  // gather table (same layout as embT)
    __shared__ float sRed[4];

    const int t = threadIdx.x;
    #pragma unroll
    for (int i = t; i < NUM_K * CDIM; i += 256)
        ((float*)sET)[i] = embT[i];     // coalesced read, conflict-free write
    __syncthreads();

    const int p = blockIdx.x * 256 + t;
    const int b = p >> 14;
    const size_t base = (size_t)b * (CDIM * HW) + (p & (HW - 1));
    const float* xp = x + base;

    v2f acc2[CDIM];                     // acc2[q] = {C_{2q}, C_{2q+1}}
    #pragma unroll
    for (int q = 0; q < CDIM; ++q) acc2[q] = (v2f){0.f, 0.f};
    float r[8];                         // numpy pairwise-tree partials for A

    // 4 groups of 8 c-steps: 8 x-loads issued per group (bounded liveness,
    // load latency overlaps previous group's 512 FMAs).
    #pragma unroll
    for (int g = 0; g < 4; ++g) {
        float xg[8];
        #pragma unroll
        for (int j = 0; j < 8; ++j)
            xg[j] = xp[(size_t)(g * 8 + j) * HW];   // coalesced across lanes
        #pragma unroll
        for (int j = 0; j < 8; ++j) {
            const int c = g * 8 + j;
            const float xc = xg[j];
            const float pp = xc * xc;               // rounds individually
            // r[j] accumulates in c-order j, j+8, j+16, j+24 (left-assoc):
            // r_j = ((p_j + p_{j+8}) + p_{j+16}) + p_{j+24}  == numpy tree
            if (g == 0) r[j] = pp; else r[j] = r[j] + pp;
            const v2f xx = (v2f){xc, xc};
            const v2f* __restrict__ e2 = (const v2f*)(embT + c * NUM_K); // uniform row
            #pragma unroll
            for (int q = 0; q < CDIM; ++q)
                acc2[q] = __builtin_elementwise_fma(xx, e2[q], acc2[q]); // per-elem fma
        }
    }
    const float A = ((r[0] + r[1]) + (r[2] + r[3])) + ((r[4] + r[5]) + (r[6] + r[7]));

    // d_k = fp32( fp32(A + B_k) - 2*C_k ) == fmaf(-2, C_k, A+B_k) bitwise.
    // Ascending k, strict <  => first-min (np.argmin). Each C_k saw the exact
    // ascending-c fp32 fma chain of the passing R3/R4 kernels.
    float best = 3.4028235e38f;
    int bi = 0;
    #pragma unroll
    for (int q = 0; q < CDIM; ++q) {
        float d0 = fmaf(-2.f, acc2[q].x, A + Bg[2 * q]);
        float d1 = fmaf(-2.f, acc2[q].y, A + Bg[2 * q + 1]);
        if (d0 < best) { best = d0; bi = 2 * q; }
        if (d1 < best) { best = d1; bi = 2 * q + 1; }
    }

    // Winner gather + coalesced stores. Loss contribution == best (the
    // squared distance we already computed; ~1e-5 abs deviation, vs 2% thr).
    float* op = outq + base;
    #pragma unroll
    for (int c = 0; c < CDIM; ++c)
        op[(size_t)c * HW] = sET[c][bi];   // bank=bi%32 gather: ~free

    float lsum = best;
    #pragma unroll
    for (int off = 32; off > 0; off >>= 1)
        lsum += __shfl_down(lsum, off, 64);
    const int wid = t >> 6;
    if ((t & 63) == 0) sRed[wid] = lsum;
    __syncthreads();
    if (t == 0) {
        double bs = (double)sRed[0] + (double)sRed[1] + (double)sRed[2] + (double)sRed[3];
        atomicAdd(ws, bs);
    }
}

__global__ void vq_finish(const double* __restrict__ ws, float* __restrict__ loss) {
    loss[0] = (float)(1.25 * ws[0] / NELEMD);
}

extern "C" void kernel_launch(void* const* d_in, const int* in_sizes, int n_in,
                              void* d_out, int out_size, void* d_ws, size_t ws_size,
                              hipStream_t stream) {
    const float* x = (const float*)d_in[0];
    const float* emb = (const float*)d_in[1];
    float* out = (float*)d_out;
    // ws layout: [0,8) double loss acc; [64,320) Bg[64]; [320,8512) embT[32][64]
    double* acc = (double*)d_ws;
    float* Bg = (float*)((char*)d_ws + 64);
    float* embT = (float*)((char*)d_ws + 320);

    hipMemsetAsync(d_ws, 0, sizeof(double), stream);
    vq_prep<<<1, 64, 0, stream>>>(emb, Bg, embT);
    vq_main<<<NPTS / 256, 256, 0, stream>>>(x, embT, Bg, out + 1, acc);
    vq_finish<<<1, 1, 0, stream>>>(acc, out);
}

// Round 10
// 84.832 us; speedup vs baseline: 2.7179x; 1.0159x over previous
//
#include <hip/hip_runtime.h>

#define NUM_K 64
#define CDIM 32
#define HW 16384          // 128*128
#define NPTS 1048576      // 64*128*128
#define NELEMD 33554432.0 // 64*32*128*128

typedef float v2f __attribute__((ext_vector_type(2)));

// numpy pairwise sum of squares, n=32 contiguous: 8 accumulators + fixed tree.
__device__ __forceinline__ float np_sumsq32(const float* v) {
#pragma clang fp contract(off)
    float r[8];
    #pragma unroll
    for (int j = 0; j < 8; ++j) {
        float p0 = v[j] * v[j];
        float p1 = v[j + 8] * v[j + 8];
        float p2 = v[j + 16] * v[j + 16];
        float p3 = v[j + 24] * v[j + 24];
        r[j] = ((p0 + p1) + p2) + p3;
    }
    return ((r[0] + r[1]) + (r[2] + r[3])) + ((r[4] + r[5]) + (r[6] + r[7]));
}

// Prep: B[k] = np.sum(emb*emb,axis=1) (numpy fp32 order) and embT[c][k]
// (transposed codebook, contiguous in k) -> global scratch.
__global__ void vq_prep(const float* __restrict__ emb, float* __restrict__ Bg,
                        float* __restrict__ embT) {
#pragma clang fp contract(off)
    int k = threadIdx.x;
    if (k < NUM_K) {
        float e[CDIM];
        #pragma unroll
        for (int c = 0; c < CDIM; ++c) e[c] = emb[k * CDIM + c];
        Bg[k] = np_sumsq32(e);
        #pragma unroll
        for (int c = 0; c < CDIM; ++c) embT[c * NUM_K + k] = e[c];
    }
}

// Loop-interchanged main (c outer, k inner) + 2-stage software pipeline:
// group g+1's x-loads are issued BEFORE group g's 256 packed FMAs consume
// cur[], so the ~600-900cyc load latency hides under the ~512cyc FMA block
// instead of serializing with it (R9's measured stall pattern).
__global__ __launch_bounds__(256) void vq_main(const float* __restrict__ x,
                                               const float* __restrict__ embT,
                                               const float* __restrict__ Bg,
                                               float* __restrict__ outq,
                                               double* __restrict__ ws) {
#pragma clang fp contract(off)
    __shared__ float sET[CDIM][NUM_K];  // gather table (same layout as embT)
    __shared__ float sRed[4];

    const int t = threadIdx.x;
    #pragma unroll
    for (int i = t; i < NUM_K * CDIM; i += 256)
        ((float*)sET)[i] = embT[i];     // coalesced read, conflict-free write
    __syncthreads();

    const int p = blockIdx.x * 256 + t;
    const int b = p >> 14;
    const size_t base = (size_t)b * (CDIM * HW) + (p & (HW - 1));
    const float* xp = x + base;

    v2f acc2[CDIM];                     // acc2[q] = {C_{2q}, C_{2q+1}}
    #pragma unroll
    for (int q = 0; q < CDIM; ++q) acc2[q] = (v2f){0.f, 0.f};
    float r[8];                         // numpy pairwise-tree partials for A

    float cur[8], nxt[8];
    #pragma unroll
    for (int j = 0; j < 8; ++j)
        cur[j] = xp[(size_t)j * HW];    // prologue: group 0 loads

    #pragma unroll
    for (int g = 0; g < 4; ++g) {
        if (g < 3) {                    // issue next group's loads FIRST
            #pragma unroll
            for (int j = 0; j < 8; ++j)
                nxt[j] = xp[(size_t)((g + 1) * 8 + j) * HW];
        }
        #pragma unroll
        for (int j = 0; j < 8; ++j) {
            const int c = g * 8 + j;
            const float xc = cur[j];
            const float pp = xc * xc;               // rounds individually
            // r_j = ((p_j + p_{j+8}) + p_{j+16}) + p_{j+24}  == numpy tree
            if (g == 0) r[j] = pp; else r[j] = r[j] + pp;
            const v2f xx = (v2f){xc, xc};
            const v2f* __restrict__ e2 = (const v2f*)(embT + c * NUM_K); // uniform row
            #pragma unroll
            for (int q = 0; q < CDIM; ++q)
                acc2[q] = __builtin_elementwise_fma(xx, e2[q], acc2[q]); // per-elem fma
        }
        if (g < 3) {
            #pragma unroll
            for (int j = 0; j < 8; ++j) cur[j] = nxt[j];   // register rotate
        }
    }
    const float A = ((r[0] + r[1]) + (r[2] + r[3])) + ((r[4] + r[5]) + (r[6] + r[7]));

    // d_k = fp32( fp32(A + B_k) - 2*C_k ) == fmaf(-2, C_k, A+B_k) bitwise.
    // Ascending k, strict <  => first-min (np.argmin). Each C_k saw the exact
    // ascending-c fp32 fma chain of the passing R3/R4/R9 kernels.
    float best = 3.4028235e38f;
    int bi = 0;
    #pragma unroll
    for (int q = 0; q < CDIM; ++q) {
        float d0 = fmaf(-2.f, acc2[q].x, A + Bg[2 * q]);
        float d1 = fmaf(-2.f, acc2[q].y, A + Bg[2 * q + 1]);
        if (d0 < best) { best = d0; bi = 2 * q; }
        if (d1 < best) { best = d1; bi = 2 * q + 1; }
    }

    // Winner gather + coalesced stores. Loss contribution == best (validated R9).
    float* op = outq + base;
    #pragma unroll
    for (int c = 0; c < CDIM; ++c)
        op[(size_t)c * HW] = sET[c][bi];   // bank=bi%32 gather: ~free

    float lsum = best;
    #pragma unroll
    for (int off = 32; off > 0; off >>= 1)
        lsum += __shfl_down(lsum, off, 64);
    const int wid = t >> 6;
    if ((t & 63) == 0) sRed[wid] = lsum;
    __syncthreads();
    if (t == 0) {
        double bs = (double)sRed[0] + (double)sRed[1] + (double)sRed[2] + (double)sRed[3];
        atomicAdd(ws, bs);
    }
}

__global__ void vq_finish(const double* __restrict__ ws, float* __restrict__ loss) {
    loss[0] = (float)(1.25 * ws[0] / NELEMD);
}

extern "C" void kernel_launch(void* const* d_in, const int* in_sizes, int n_in,
                              void* d_out, int out_size, void* d_ws, size_t ws_size,
                              hipStream_t stream) {
    const float* x = (const float*)d_in[0];
    const float* emb = (const float*)d_in[1];
    float* out = (float*)d_out;
    // ws layout: [0,8) double loss acc; [64,320) Bg[64]; [320,8512) embT[32][64]
    double* acc = (double*)d_ws;
    float* Bg = (float*)((char*)d_ws + 64);
    float* embT = (float*)((char*)d_ws + 320);

    hipMemsetAsync(d_ws, 0, sizeof(double), stream);
    vq_prep<<<1, 64, 0, stream>>>(emb, Bg, embT);
    vq_main<<<NPTS / 256, 256, 0, stream>>>(x, embT, Bg, out + 1, acc);
    vq_finish<<<1, 1, 0, stream>>>(acc, out);
}